// Round 3
// baseline (1085.830 us; speedup 1.0000x reference)
//
#include <hip/hip_runtime.h>
#include <math.h>

// WaveLM: logits[b,t,v] = sum_{t'<t} g(id[b,t'], v)
// g(u,v) = 2 * sum_{i,j in 1..H} (A_u/i^dec)(A_v/j^dec) * sinc(2*(f_u*i - f_v*j))
// sinc(2d) = sin(2*pi*d)/(2*pi*d), sinc(0)=1
//
// R8: - R7 kept (GT=16 fused segment scan, id-only prefetch, bases+addbase).
//     - FIX: wavelm_g at __launch_bounds__(256, 8): R6/R7 showed the compiler
//       software-pipelines the 28 u-side s_loads on its own, hits the SGPR
//       cap (112) and spills ~20 values to VGPRs (64->84), halving residency
//       (4 waves/SIMD instead of 8, occupancy 27%). Capping at 8 waves/EU
//       forces VGPR<=64 (R5 proved the body fits) so the allocator stops
//       pipelining past the budget instead of spilling.
//     - hot inner loop numerically identical to R5 (packed fp32 via inline
//       asm v_pk_*, batched inversion, guarded rare path).

typedef float v2f __attribute__((ext_vector_type(2)));
typedef float v4f __attribute__((ext_vector_type(4)));

constexpr int cB = 4, cT = 512, cV = 8000, cH = 7;
constexpr int GT = 16;                // tokens per wavelm_g block == seglen
constexpr int NSEG = cT / GT;         // 32 segments
constexpr int NPLANE = 28;            // table planes

__device__ __forceinline__ v2f pk_add(v2f a, v2f b) {
    v2f d; asm("v_pk_add_f32 %0, %1, %2" : "=v"(d) : "v"(a), "v"(b)); return d;
}
__device__ __forceinline__ v2f pk_mul(v2f a, v2f b) {
    v2f d; asm("v_pk_mul_f32 %0, %1, %2" : "=v"(d) : "v"(a), "v"(b)); return d;
}
__device__ __forceinline__ v2f pk_fma(v2f a, v2f b, v2f c) {
    v2f d; asm("v_pk_fma_f32 %0, %1, %2, %3" : "=v"(d) : "v"(a), "v"(b), "v"(c));
    return d;
}

__global__ __launch_bounds__(256) void wavelm_tab(
    const float* __restrict__ freq, const float* __restrict__ amp,
    const float* __restrict__ decay_p, float* __restrict__ tab)
{
    const int v = blockIdx.x * 256 + threadIdx.x;
    if (v >= cV) return;
    const float decay = decay_p[0];
    const float f = freq[v], A = amp[v];
    const float p2 = __builtin_amdgcn_exp2f(-decay);
    const float p3 = __builtin_amdgcn_exp2f(-decay * 1.5849625007f);
    const float p5 = __builtin_amdgcn_exp2f(-decay * 2.3219280949f);
    const float p7 = __builtin_amdgcn_exp2f(-decay * 2.8073549221f);
    const float rp[7] = {1.f, p2, p3, p2*p2, p5, p2*p3, p7};
    const float xr = f - rintf(f);
    const float s1 = __builtin_amdgcn_sinf(xr);
    const float c1 = __builtin_amdgcn_cosf(xr);
    float s = s1, c = c1;
#pragma unroll
    for (int k = 0; k < cH; ++k) {
        if (k) { const float sp = s, cp = c;
                 s = fmaf(sp, c1,  cp * s1);
                 c = fmaf(cp, c1, -(sp * s1)); }
        tab[(size_t)k * cV + v]        = s;
        tab[(size_t)(7 + k) * cV + v]  = c;
        tab[(size_t)(14 + k) * cV + v] = A * rp[k];
        tab[(size_t)(21 + k) * cV + v] = f * (float)(k + 1);
    }
}

__global__ __launch_bounds__(256, 8) void wavelm_g(
    const int* __restrict__ ids, const float* __restrict__ tab,
    float* __restrict__ out, float* __restrict__ segsum, const int segmode)
{
    const int bs  = blockIdx.y;                     // (b, seg) flattened
    const int bt0 = bs * GT;
    const int vh  = blockIdx.x * 256 + threadIdx.x; // v-pair index
    const bool valid = (vh * 2 < cV);
    const int vc = valid ? vh : 0;

    // ---- v-side setup once, amortized over GT tokens ----
    const v2f* tp = (const v2f*)tab;                // plane k: k*(cV/2)+vc
    v2f nb[cH], sBw[cH], cBw[cH];
#pragma unroll
    for (int j = 0; j < cH; ++j) {
        const v2f s = tp[(size_t)j * (cV/2) + vc];
        const v2f c = tp[(size_t)(7 + j) * (cV/2) + vc];
        const v2f w = tp[(size_t)(14 + j) * (cV/2) + vc];
        const v2f a = tp[(size_t)(21 + j) * (cV/2) + vc];
        const v2f ws = w * 0.15915494309189535f;    // w/(2pi)
        sBw[j] = s * ws;
        cBw[j] = c * ws;
        nb[j].x = -a.x;  nb[j].y = -a.y;            // negated: d = aU + nb
    }

    v2f acc;  acc.x = 0.f;  acc.y = 0.f;            // running segment prefix

    int idc = ids[bt0];                             // current token id (SGPR)
    for (int g = 0; g < GT; ++g) {
        // prefetch only the NEXT id (1 SGPR); breaks the id->tab serial chain
        const int idn = (g + 1 < GT) ? ids[bt0 + g + 1] : idc;

        // u-side: 28 wave-uniform scalar loads, address known at loop top
        float sA[cH], cA[cH], wA[cH], aU[cH];
#pragma unroll
        for (int i = 0; i < cH; ++i) {
            sA[i] = tab[(size_t)i * cV + idc];
            cA[i] = tab[(size_t)(7 + i) * cV + idc];
            wA[i] = tab[(size_t)(14 + i) * cV + idc];
            aU[i] = tab[(size_t)(21 + i) * cV + idc];
        }

        float accx = 0.f, accy = 0.f;
        float mn = 3.0e38f, mx = 0.0f;
#pragma unroll
        for (int i = 0; i < cH; ++i) {
            v2f ai;  ai.x = aU[i];  ai.y = aU[i];
            v2f d[cH], p[cH];
#pragma unroll
            for (int j = 0; j < cH; ++j) d[j] = pk_add(ai, nb[j]);
            p[0] = d[0];
#pragma unroll
            for (int j = 1; j < cH; ++j) p[j] = pk_mul(p[j-1], d[j]);
            const float ptot = p[6].x * p[6].y;
            mn = fminf(mn, fminf(fabsf(p[6].x), fabsf(p[6].y)));
            mn = fminf(mn, fabsf(ptot));
            mx = fmaxf(mx, fabsf(ptot));
            const float rt = __builtin_amdgcn_rcpf(ptot);
            v2f r;  r.x = rt * p[6].y;  r.y = rt * p[6].x;   // 1/p6 per comp
            v2f accS = (v2f)0.f, accC = (v2f)0.f;
#pragma unroll
            for (int j = cH - 1; j >= 1; --j) {
                const v2f inv = pk_mul(r, p[j-1]);
                accS = pk_fma(cBw[j], inv, accS);
                accC = pk_fma(sBw[j], inv, accC);
                r = pk_mul(r, d[j]);
            }
            accS = pk_fma(cBw[0], r, accS);
            accC = pk_fma(sBw[0], r, accC);
            // sum_j sn_j*inv_j = sA_i*accS - cA_i*accC  (per component)
            const float tx = fmaf(sA[i], accS.x, -(cA[i] * accC.x));
            const float ty = fmaf(sA[i], accS.y, -(cA[i] * accC.y));
            accx = fmaf(wA[i], tx, accx);
            accy = fmaf(wA[i], ty, accy);
        }

        // rare guarded path: exact-zero d (v==id), underflow, overflow
        if (mn < 1e-37f || mx > 1e37f) {
            accx = 0.f;  accy = 0.f;
#pragma unroll
            for (int i = 0; i < cH; ++i) {
                float ax = 0.f, ay = 0.f;
#pragma unroll
                for (int j = 0; j < cH; ++j) {
                    const v2f w = tp[(size_t)(14 + j) * (cV/2) + vc];
                    const float dx = aU[i] + nb[j].x;
                    const float dy = aU[i] + nb[j].y;
                    const float snx = fmaf(sA[i], cBw[j].x, -(cA[i] * sBw[j].x));
                    const float sny = fmaf(sA[i], cBw[j].y, -(cA[i] * sBw[j].y));
                    float qx = snx * __builtin_amdgcn_rcpf(dx);
                    float qy = sny * __builtin_amdgcn_rcpf(dy);
                    qx = (dx == 0.f) ? w.x : qx;
                    qy = (dy == 0.f) ? w.y : qy;
                    ax += qx;  ay += qy;
                }
                accx = fmaf(wA[i], ax, accx);
                accy = fmaf(wA[i], ay, accy);
            }
        }

        if (valid) {
            v2f res;  res.x = 2.f * accx;  res.y = 2.f * accy;
            const size_t o = (size_t)(bt0 + g) * cV + (size_t)vh * 2;
            // segmode: write shifted local prefix; else raw value
            v2f wv;  wv.x = segmode ? acc.x : res.x;
                     wv.y = segmode ? acc.y : res.y;
            *(v2f*)(out + o) = wv;
            acc = pk_add(acc, res);
        }

        idc = idn;
    }

    if (valid && segmode)
        *(v2f*)(segsum + (size_t)bs * cV + (size_t)vh * 2) = acc;
}

// in-place exclusive scan of the NSEG segment sums per (b, v)
__global__ __launch_bounds__(256) void wavelm_bases(float* __restrict__ segsum)
{
    const int g = blockIdx.x * 256 + threadIdx.x;
    if (g >= cB * cV) return;
    const int b = g / cV;
    const int v = g - b * cV;
    float* p = segsum + (size_t)b * NSEG * cV + v;
    float acc = 0.f;
#pragma unroll
    for (int s = 0; s < NSEG; ++s) {
        const float t = p[(size_t)s * cV];
        p[(size_t)s * cV] = acc;
        acc += t;
    }
}

// out[b,t,v] += base(b, t/GT, v); float4 x 8 consecutive t per thread
__global__ __launch_bounds__(256) void wavelm_addbase(
    float* __restrict__ out, const float* __restrict__ bases)
{
    const int btq = blockIdx.y;          // b*(cT/8) + t-octet
    const int b  = btq >> 6;             // cT/8 = 64
    const int t0 = (btq & 63) * 8;
    const int seg = t0 / GT;
    if (seg == 0) return;                // base is zero: out already final
    const int v4 = blockIdx.x * 256 + threadIdx.x;
    if (v4 >= cV / 4) return;

    const v4f base = *(const v4f*)(bases +
        ((size_t)(b * NSEG + seg)) * cV + (size_t)v4 * 4);
    float* p = out + ((size_t)b * cT + t0) * cV + (size_t)v4 * 4;
#pragma unroll
    for (int k = 0; k < 8; ++k) {
        v4f x = *(v4f*)(p + (size_t)k * cV);
        x.x += base.x;  x.y += base.y;  x.z += base.z;  x.w += base.w;
        *(v4f*)(p + (size_t)k * cV) = x;
    }
}

// fallback full-chain scan (ws too small for segsum)
__global__ __launch_bounds__(256) void wavelm_scan(float* __restrict__ out)
{
    const int g = blockIdx.x * blockDim.x + threadIdx.x;
    if (g >= cB * cV) return;
    const int b = g / cV;
    const int v = g - b * cV;
    float* p = out + (size_t)b * cT * cV + v;
    float acc = 0.f;
#pragma unroll 8
    for (int t = 0; t < cT; ++t) {
        const float c = p[(size_t)t * cV];
        p[(size_t)t * cV] = acc;
        acc += c;
    }
}

extern "C" void kernel_launch(void* const* d_in, const int* in_sizes, int n_in,
                              void* d_out, int out_size, void* d_ws, size_t ws_size,
                              hipStream_t stream)
{
    const int*   ids  = (const int*)d_in[0];
    const float* freq = (const float*)d_in[1];
    const float* amp  = (const float*)d_in[2];
    const float* dec  = (const float*)d_in[3];
    float* out = (float*)d_out;
    float* tab = (float*)d_ws;                           // 28*8000*4 = 896 KB
    float* segsum = tab + (size_t)NPLANE * cV;           // 4*32*8000*4 = 4 MB

    const size_t tab_b = (size_t)NPLANE * cV * sizeof(float);
    const size_t seg_b = (size_t)cB * NSEG * cV * sizeof(float);
    const int segmode = (tab_b + seg_b <= ws_size) ? 1 : 0;

    wavelm_tab<<<(cV + 255) / 256, 256, 0, stream>>>(freq, amp, dec, tab);

    dim3 grid((cV / 2 + 255) / 256, cB * cT / GT);       // 16 x 128
    wavelm_g<<<grid, dim3(256), 0, stream>>>(ids, tab, out, segsum, segmode);

    if (segmode) {
        const int nchains = cB * cV;
        wavelm_bases<<<(nchains + 255) / 256, dim3(256), 0, stream>>>(segsum);
        dim3 ab((cV / 4 + 255) / 256, cB * (cT / 8));    // 8 x 256
        wavelm_addbase<<<ab, dim3(256), 0, stream>>>(out, segsum);
    } else {
        const int nchains = cB * cV;
        wavelm_scan<<<(nchains + 255) / 256, dim3(256), 0, stream>>>(out);
    }
}

// Round 4
// 211.966 us; speedup vs baseline: 5.1227x; 5.1227x over previous
//
#include <hip/hip_runtime.h>
#include <math.h>

// WaveLM: logits[b,t,v] = sum_{t'<t} g(id[b,t'], v)
// g(u,v) = 2 * sum_{i,j in 1..H} (A_u/i^dec)(A_v/j^dec) * sinc(2*(f_u*i - f_v*j))
// sinc(2d) = sin(2*pi*d)/(2*pi*d), sinc(0)=1
//
// R9: - R8's __launch_bounds__(256,8) REVERTED (VGPR forced to 32 -> full
//       scratch spill, 2.4GB fetch, 1ms). No occupancy arg on wavelm_g.
//     - u-side compression: per token load only {f, A, s1, c1} (4 s_loads,
//       not 28). sin/cos(2pi f k) derived by the SAME angle-addition
//       recurrence wavelm_tab uses (bit-identical); aU[i] = f*(i+1) same op
//       as tab; rp[] (decay powers) computed once per block exactly as tab;
//       A and the 2x folded out of the i-loop. SGPR footprint/token drops
//       7x so the compiler's token pipeline stays in SGPRs (R6/R7 leaked
//       ~20 values into VGPRs -> 84 VGPR, 27% occupancy).
//     - wavelm_bases fused into wavelm_addbase (each block sums its own
//       <=31 L2-resident segsum rows); one fewer launch.
//     - GT=16 fused segment scan + id-only prefetch kept from R7.

typedef float v2f __attribute__((ext_vector_type(2)));
typedef float v4f __attribute__((ext_vector_type(4)));

constexpr int cB = 4, cT = 512, cV = 8000, cH = 7;
constexpr int GT = 16;                // tokens per wavelm_g block == seglen
constexpr int NSEG = cT / GT;         // 32 segments
constexpr int NPLANE = 28;            // table planes

__device__ __forceinline__ v2f pk_add(v2f a, v2f b) {
    v2f d; asm("v_pk_add_f32 %0, %1, %2" : "=v"(d) : "v"(a), "v"(b)); return d;
}
__device__ __forceinline__ v2f pk_mul(v2f a, v2f b) {
    v2f d; asm("v_pk_mul_f32 %0, %1, %2" : "=v"(d) : "v"(a), "v"(b)); return d;
}
__device__ __forceinline__ v2f pk_fma(v2f a, v2f b, v2f c) {
    v2f d; asm("v_pk_fma_f32 %0, %1, %2, %3" : "=v"(d) : "v"(a), "v"(b), "v"(c));
    return d;
}

__global__ __launch_bounds__(256) void wavelm_tab(
    const float* __restrict__ freq, const float* __restrict__ amp,
    const float* __restrict__ decay_p, float* __restrict__ tab)
{
    const int v = blockIdx.x * 256 + threadIdx.x;
    if (v >= cV) return;
    const float decay = decay_p[0];
    const float f = freq[v], A = amp[v];
    const float p2 = __builtin_amdgcn_exp2f(-decay);
    const float p3 = __builtin_amdgcn_exp2f(-decay * 1.5849625007f);
    const float p5 = __builtin_amdgcn_exp2f(-decay * 2.3219280949f);
    const float p7 = __builtin_amdgcn_exp2f(-decay * 2.8073549221f);
    const float rp[7] = {1.f, p2, p3, p2*p2, p5, p2*p3, p7};
    const float xr = f - rintf(f);
    const float s1 = __builtin_amdgcn_sinf(xr);
    const float c1 = __builtin_amdgcn_cosf(xr);
    float s = s1, c = c1;
#pragma unroll
    for (int k = 0; k < cH; ++k) {
        if (k) { const float sp = s, cp = c;
                 s = fmaf(sp, c1,  cp * s1);
                 c = fmaf(cp, c1, -(sp * s1)); }
        tab[(size_t)k * cV + v]        = s;
        tab[(size_t)(7 + k) * cV + v]  = c;
        tab[(size_t)(14 + k) * cV + v] = A * rp[k];
        tab[(size_t)(21 + k) * cV + v] = f * (float)(k + 1);
    }
}

__global__ __launch_bounds__(256) void wavelm_g(
    const int* __restrict__ ids, const float* __restrict__ tab,
    const float* __restrict__ decay_p,
    float* __restrict__ out, float* __restrict__ segsum, const int segmode)
{
    const int bs  = blockIdx.y;                     // (b, seg) flattened
    const int bt0 = bs * GT;
    const int vh  = blockIdx.x * 256 + threadIdx.x; // v-pair index
    const bool valid = (vh * 2 < cV);
    const int vc = valid ? vh : 0;

    // ---- v-side setup once, amortized over GT tokens ----
    const v2f* tp = (const v2f*)tab;                // plane k: k*(cV/2)+vc
    v2f nb[cH], sBw[cH], cBw[cH];
#pragma unroll
    for (int j = 0; j < cH; ++j) {
        const v2f s = tp[(size_t)j * (cV/2) + vc];
        const v2f c = tp[(size_t)(7 + j) * (cV/2) + vc];
        const v2f w = tp[(size_t)(14 + j) * (cV/2) + vc];
        const v2f a = tp[(size_t)(21 + j) * (cV/2) + vc];
        const v2f ws = w * 0.15915494309189535f;    // w/(2pi)
        sBw[j] = s * ws;
        cBw[j] = c * ws;
        nb[j].x = -a.x;  nb[j].y = -a.y;            // negated: d = aU + nb
    }

    // rp[k] = (k+1)^-decay, uniform across lanes; identical ops to wavelm_tab
    const float decay = decay_p[0];
    const float q2 = __builtin_amdgcn_exp2f(-decay);
    const float q3 = __builtin_amdgcn_exp2f(-decay * 1.5849625007f);
    const float q5 = __builtin_amdgcn_exp2f(-decay * 2.3219280949f);
    const float q7 = __builtin_amdgcn_exp2f(-decay * 2.8073549221f);
    const float rp[7] = {1.f, q2, q3, q2*q2, q5, q2*q3, q7};

    v2f acc;  acc.x = 0.f;  acc.y = 0.f;            // running segment prefix

    int idc = ids[bt0];                             // current token id (SGPR)
    for (int g = 0; g < GT; ++g) {
        // prefetch only the NEXT id (1 SGPR); breaks the id->tab serial chain
        const int idn = (g + 1 < GT) ? ids[bt0 + g + 1] : idc;

        // u-side: 4 wave-uniform scalar loads; rest derived in-register
        const float fu  = tab[(size_t)21 * cV + idc];   // f*1 == f
        const float Au  = tab[(size_t)14 * cV + idc];   // A*rp[0] == A
        const float s1u = tab[idc];                     // sin(2pi f)
        const float c1u = tab[(size_t)7 * cV + idc];    // cos(2pi f)

        float accx = 0.f, accy = 0.f;
        float mn = 3.0e38f, mx = 0.0f;
        float su = s1u, cu = c1u;                   // sin/cos(2pi f (i+1))
#pragma unroll
        for (int i = 0; i < cH; ++i) {
            if (i) { const float sp = su, cp = cu;
                     su = fmaf(sp, c1u,  cp * s1u);
                     cu = fmaf(cp, c1u, -(sp * s1u)); }
            const float au = fu * (float)(i + 1);   // same op as tab plane 21
            v2f ai;  ai.x = au;  ai.y = au;
            v2f d[cH], p[cH];
#pragma unroll
            for (int j = 0; j < cH; ++j) d[j] = pk_add(ai, nb[j]);
            p[0] = d[0];
#pragma unroll
            for (int j = 1; j < cH; ++j) p[j] = pk_mul(p[j-1], d[j]);
            const float ptot = p[6].x * p[6].y;
            mn = fminf(mn, fminf(fabsf(p[6].x), fabsf(p[6].y)));
            mn = fminf(mn, fabsf(ptot));
            mx = fmaxf(mx, fabsf(ptot));
            const float rt = __builtin_amdgcn_rcpf(ptot);
            v2f r;  r.x = rt * p[6].y;  r.y = rt * p[6].x;   // 1/p6 per comp
            v2f accS = (v2f)0.f, accC = (v2f)0.f;
#pragma unroll
            for (int j = cH - 1; j >= 1; --j) {
                const v2f inv = pk_mul(r, p[j-1]);
                accS = pk_fma(cBw[j], inv, accS);
                accC = pk_fma(sBw[j], inv, accC);
                r = pk_mul(r, d[j]);
            }
            accS = pk_fma(cBw[0], r, accS);
            accC = pk_fma(sBw[0], r, accC);
            // sum_j sn_j*inv_j = su*accS - cu*accC  (per component)
            const float tx = fmaf(su, accS.x, -(cu * accC.x));
            const float ty = fmaf(su, accS.y, -(cu * accC.y));
            accx = fmaf(rp[i], tx, accx);
            accy = fmaf(rp[i], ty, accy);
        }

        // rare guarded path: exact-zero d (v==id), underflow, overflow
        if (mn < 1e-37f || mx > 1e37f) {
            accx = 0.f;  accy = 0.f;
            float s2 = s1u, c2 = c1u;
#pragma unroll
            for (int i = 0; i < cH; ++i) {
                if (i) { const float sp = s2, cp = c2;
                         s2 = fmaf(sp, c1u,  cp * s1u);
                         c2 = fmaf(cp, c1u, -(sp * s1u)); }
                const float au = fu * (float)(i + 1);
                float ax = 0.f, ay = 0.f;
#pragma unroll
                for (int j = 0; j < cH; ++j) {
                    const v2f w = tp[(size_t)(14 + j) * (cV/2) + vc];
                    const float dx = au + nb[j].x;
                    const float dy = au + nb[j].y;
                    const float snx = fmaf(s2, cBw[j].x, -(c2 * sBw[j].x));
                    const float sny = fmaf(s2, cBw[j].y, -(c2 * sBw[j].y));
                    float qx = snx * __builtin_amdgcn_rcpf(dx);
                    float qy = sny * __builtin_amdgcn_rcpf(dy);
                    qx = (dx == 0.f) ? w.x : qx;
                    qy = (dy == 0.f) ? w.y : qy;
                    ax += qx;  ay += qy;
                }
                accx = fmaf(rp[i], ax, accx);
                accy = fmaf(rp[i], ay, accy);
            }
        }

        if (valid) {
            const float A2 = 2.f * Au;
            v2f res;  res.x = A2 * accx;  res.y = A2 * accy;
            const size_t o = (size_t)(bt0 + g) * cV + (size_t)vh * 2;
            // segmode: write shifted local prefix; else raw value
            v2f wv;  wv.x = segmode ? acc.x : res.x;
                     wv.y = segmode ? acc.y : res.y;
            *(v2f*)(out + o) = wv;
            acc = pk_add(acc, res);
        }

        idc = idn;
    }

    if (valid && segmode)
        *(v2f*)(segsum + (size_t)bs * cV + (size_t)vh * 2) = acc;
}

// out[b,t,v] += sum_{sp<seg} segsum[b,sp,v]; lookback fused (bases kernel
// eliminated); segsum is 4MB -> L2/L3-resident for the re-reads.
__global__ __launch_bounds__(256) void wavelm_addbase(
    float* __restrict__ out, const float* __restrict__ segsum)
{
    const int btq = blockIdx.y;          // b*(cT/8) + t-octet
    const int b  = btq >> 6;             // cT/8 = 64
    const int t0 = (btq & 63) * 8;
    const int seg = t0 / GT;
    if (seg == 0) return;                // base is zero: out already final
    const int v4 = blockIdx.x * 256 + threadIdx.x;
    if (v4 >= cV / 4) return;

    const float* sp = segsum + (size_t)b * NSEG * cV + (size_t)v4 * 4;
    v4f base;  base.x = 0.f;  base.y = 0.f;  base.z = 0.f;  base.w = 0.f;
    for (int s = 0; s < seg; ++s) {
        const v4f x = *(const v4f*)(sp + (size_t)s * cV);
        base.x += x.x;  base.y += x.y;  base.z += x.z;  base.w += x.w;
    }

    float* p = out + ((size_t)b * cT + t0) * cV + (size_t)v4 * 4;
#pragma unroll
    for (int k = 0; k < 8; ++k) {
        v4f x = *(v4f*)(p + (size_t)k * cV);
        x.x += base.x;  x.y += base.y;  x.z += base.z;  x.w += base.w;
        *(v4f*)(p + (size_t)k * cV) = x;
    }
}

// fallback full-chain scan (ws too small for segsum)
__global__ __launch_bounds__(256) void wavelm_scan(float* __restrict__ out)
{
    const int g = blockIdx.x * blockDim.x + threadIdx.x;
    if (g >= cB * cV) return;
    const int b = g / cV;
    const int v = g - b * cV;
    float* p = out + (size_t)b * cT * cV + v;
    float acc = 0.f;
#pragma unroll 8
    for (int t = 0; t < cT; ++t) {
        const float c = p[(size_t)t * cV];
        p[(size_t)t * cV] = acc;
        acc += c;
    }
}

extern "C" void kernel_launch(void* const* d_in, const int* in_sizes, int n_in,
                              void* d_out, int out_size, void* d_ws, size_t ws_size,
                              hipStream_t stream)
{
    const int*   ids  = (const int*)d_in[0];
    const float* freq = (const float*)d_in[1];
    const float* amp  = (const float*)d_in[2];
    const float* dec  = (const float*)d_in[3];
    float* out = (float*)d_out;
    float* tab = (float*)d_ws;                           // 28*8000*4 = 896 KB
    float* segsum = tab + (size_t)NPLANE * cV;           // 4*32*8000*4 = 4 MB

    const size_t tab_b = (size_t)NPLANE * cV * sizeof(float);
    const size_t seg_b = (size_t)cB * NSEG * cV * sizeof(float);
    const int segmode = (tab_b + seg_b <= ws_size) ? 1 : 0;

    wavelm_tab<<<(cV + 255) / 256, 256, 0, stream>>>(freq, amp, dec, tab);

    dim3 grid((cV / 2 + 255) / 256, cB * cT / GT);       // 16 x 128
    wavelm_g<<<grid, dim3(256), 0, stream>>>(ids, tab, dec, out, segsum, segmode);

    if (segmode) {
        dim3 ab((cV / 4 + 255) / 256, cB * (cT / 8));    // 8 x 256
        wavelm_addbase<<<ab, dim3(256), 0, stream>>>(out, segsum);
    } else {
        const int nchains = cB * cV;
        wavelm_scan<<<(nchains + 255) / 256, dim3(256), 0, stream>>>(out);
    }
}